// Round 1
// baseline (114.195 us; speedup 1.0000x reference)
//
#include <hip/hip_runtime.h>

// Problem constants: B=8, N=128, T=64, EMBED=64, HEADS=8, HEAD_DIM=8
// V/K/Q/Out layout: (b, n, t, c) fp32, element strides (524288, 4096, 64, 1).
// Round-5 evidence: MfmaUtil=0 with VALU(35us)+LDS(30us) co-bound on matmul work.
// MFMA version (114.8us): E^T = K'Q'^T trick keeps P in A-layout for PV.
// Round-7 (this): latency theory. Strip critical path shortened:
//   - P packed to f16 UNNORMALIZED right after exp2 (PV no longer waits on
//     sum -> rcp -> 32 normalize muls); output scaled by inv at the end.
//     inv is per q=lane&15 but o rows are q=quad*4+r -> 4x __shfl(width 16).
//   - PV split into two 4-deep MFMA chains (halved serial latency).
//   - 4-way partial sums; cross-lane reduction placed after PV issue so
//     shuffle+rcp latency hides under the MFMAs.
//   - live VGPRs ~106 < 128 cap of __launch_bounds__(512,4) -> no spills.

typedef _Float16 half4 __attribute__((ext_vector_type(4)));
typedef float    f32x4 __attribute__((ext_vector_type(4)));

#define MFMA16(a,b,c) __builtin_amdgcn_mfma_f32_16x16x16f16((a),(b),(c),0,0,0)

__device__ __forceinline__ unsigned short f2h(float f){
    union { _Float16 h; unsigned short u; } c; c.h = (_Float16)f; return c.u;
}

// LDS offsets in halves (ushort units). Total 37640 halves = 75280 B -> 2 blocks/CU.
#define ZS 0          //    8 halves zero scratch (b64-read target for padded lanes)
#define KB 8          // K' per head: [128 k][8 d]            8*1024
#define QB 8200       // Q' per head: [128 q][8 d] (pre-scaled by sc)
#define VB 16392      // V'^T per head: [8 e][128 k]
#define CB 24584      // C': [128 n][68]  (stride 68 -> conflict-free fc reads)
#define WB 33288      // Wo: [64 o][68]
#define LDS_TOTAL 37640

__global__ __launch_bounds__(512, 4)
void sattn_kernel(const float* __restrict__ V,
                  const float* __restrict__ K,
                  const float* __restrict__ Q,
                  const float* __restrict__ Wv,
                  const float* __restrict__ Wk,
                  const float* __restrict__ Wq,
                  const float* __restrict__ Wo,
                  const float* __restrict__ bo,
                  float* __restrict__ Out)
{
    __shared__ __align__(16) unsigned short smem[LDS_TOTAL];

    const int tid  = threadIdx.x;
    const int bid  = blockIdx.x;
    const int b    = bid >> 6;
    const int t    = bid & 63;
    const long base = (long)b * 524288 + t * 64;
    const float SC = 0.18033688011112043f;   // (1/8) * log2(e), folded into Q'

    // ---- zero scratch ----
    if (tid < 4) *(unsigned int*)(smem + tid*2) = 0u;

    // ---- stage Wo f16 [64 o][68] ----
    {
        int o = tid >> 3, c8 = tid & 7;
        const float* ws = Wo + o*64 + c8*8;
        float4 a = *(const float4*)ws;
        float4 d = *(const float4*)(ws + 4);
        half4 h0; h0.x=(_Float16)a.x; h0.y=(_Float16)a.y; h0.z=(_Float16)a.z; h0.w=(_Float16)a.w;
        half4 h1; h1.x=(_Float16)d.x; h1.y=(_Float16)d.y; h1.z=(_Float16)d.z; h1.w=(_Float16)d.w;
        *(half4*)(smem + WB + o*68 + c8*8)     = h0;   // 8-B aligned
        *(half4*)(smem + WB + o*68 + c8*8 + 4) = h1;
    }

    // ---- stage projected K', Q' (x sc), V'^T as f16 (2 cells/thread) ----
    #pragma unroll
    for (int i = 0; i < 2; ++i){
        int id = i*512 + tid;
        int cn = id >> 3, ch = id & 7;          // key/query row, head
        const float* pk = K + base + cn*4096 + ch*8;
        const float* pv = V + base + cn*4096 + ch*8;
        const float* pq = Q + base + cn*4096 + ch*8;
        float4 ka = *(const float4*)pk, kb = *(const float4*)(pk+4);
        float4 va = *(const float4*)pv, vb = *(const float4*)(pv+4);
        float4 qa = *(const float4*)pq, qb = *(const float4*)(pq+4);
        float ok[8], ov[8], oq[8];
        #pragma unroll
        for (int e = 0; e < 8; ++e){
            float4 wk0 = *(const float4*)(Wk + e*8), wk1 = *(const float4*)(Wk + e*8 + 4);
            float4 wv0 = *(const float4*)(Wv + e*8), wv1 = *(const float4*)(Wv + e*8 + 4);
            float4 wq0 = *(const float4*)(Wq + e*8), wq1 = *(const float4*)(Wq + e*8 + 4);
            ok[e] = ka.x*wk0.x + ka.y*wk0.y + ka.z*wk0.z + ka.w*wk0.w
                  + kb.x*wk1.x + kb.y*wk1.y + kb.z*wk1.z + kb.w*wk1.w;
            ov[e] = va.x*wv0.x + va.y*wv0.y + va.z*wv0.z + va.w*wv0.w
                  + vb.x*wv1.x + vb.y*wv1.y + vb.z*wv1.z + vb.w*wv1.w;
            oq[e] = (qa.x*wq0.x + qa.y*wq0.y + qa.z*wq0.z + qa.w*wq0.w
                  +  qb.x*wq1.x + qb.y*wq1.y + qb.z*wq1.z + qb.w*wq1.w) * SC;
        }
        half4 k0; k0.x=(_Float16)ok[0]; k0.y=(_Float16)ok[1]; k0.z=(_Float16)ok[2]; k0.w=(_Float16)ok[3];
        half4 k1; k1.x=(_Float16)ok[4]; k1.y=(_Float16)ok[5]; k1.z=(_Float16)ok[6]; k1.w=(_Float16)ok[7];
        half4 q0; q0.x=(_Float16)oq[0]; q0.y=(_Float16)oq[1]; q0.z=(_Float16)oq[2]; q0.w=(_Float16)oq[3];
        half4 q1; q1.x=(_Float16)oq[4]; q1.y=(_Float16)oq[5]; q1.z=(_Float16)oq[6]; q1.w=(_Float16)oq[7];
        *(half4*)(smem + KB + ch*1024 + cn*8)     = k0;
        *(half4*)(smem + KB + ch*1024 + cn*8 + 4) = k1;
        *(half4*)(smem + QB + ch*1024 + cn*8)     = q0;
        *(half4*)(smem + QB + ch*1024 + cn*8 + 4) = q1;
        #pragma unroll
        for (int e = 0; e < 8; ++e)
            smem[VB + ch*1024 + e*128 + cn] = f2h(ov[e]);
    }

    __syncthreads();

    // ---- attention: wave = head h ----
    const int h    = tid >> 6;
    const int q16  = tid & 15;          // lane & 15
    const int quad = (tid & 63) >> 4;   // lane >> 4
    const f32x4 zz = {0.f, 0.f, 0.f, 0.f};

    // K' A-fragments (8 k-tiles, held): A[m=l&15][k=quad*4+i], quads 2,3 -> zero
    half4 kf[8];
    #pragma unroll
    for (int mt = 0; mt < 8; ++mt){
        int a = KB + h*1024 + (mt*16 + q16)*8 + quad*4;
        if (quad >= 2) a = ZS;
        kf[mt] = *(const half4*)(smem + a);
    }
    // V'^T B-fragments (8 k-steps, held): B[k=quad*4+i][n=e=l&15], e>=8 -> zero
    half4 vf[8];
    #pragma unroll
    for (int s = 0; s < 8; ++s){
        int a = VB + h*1024 + q16*128 + s*16 + quad*4;
        if (q16 >= 8) a = ZS;
        vf[s] = *(const half4*)(smem + a);
    }

    #pragma unroll 1
    for (int qs = 0; qs < 8; ++qs){
        // Q' B-fragment for this strip: B[k=d][n=q], quads 2,3 -> zero
        int qa = QB + h*1024 + (qs*16 + q16)*8 + quad*4;
        if (quad >= 2) qa = ZS;
        half4 qf = *(const half4*)(smem + qa);

        // E^T strip: 8 independent MFMAs (m-tile = key tile)
        f32x4 acc[8];
        #pragma unroll
        for (int mt = 0; mt < 8; ++mt)
            acc[mt] = MFMA16(kf[mt], qf, zz);

        // softmax (no max-sub: |E*sc| <~ 3 by construction): exp2,
        // pack P to f16 UNNORMALIZED immediately (PV doesn't wait on the sum)
        half4 pf[8];
        float s0 = 0.f, s1 = 0.f, s2 = 0.f, s3 = 0.f;
        #pragma unroll
        for (int mt = 0; mt < 8; ++mt){
            float p0 = __builtin_amdgcn_exp2f(acc[mt][0]);
            float p1 = __builtin_amdgcn_exp2f(acc[mt][1]);
            float p2 = __builtin_amdgcn_exp2f(acc[mt][2]);
            float p3 = __builtin_amdgcn_exp2f(acc[mt][3]);
            s0 += p0; s1 += p1; s2 += p2; s3 += p3;
            pf[mt].x = (_Float16)p0; pf[mt].y = (_Float16)p1;
            pf[mt].z = (_Float16)p2; pf[mt].w = (_Float16)p3;
        }

        // PV: two 4-deep chains (issue ASAP; the reduction below overlaps)
        f32x4 o0 = zz, o1 = zz;
        #pragma unroll
        for (int s8 = 0; s8 < 4; ++s8){
            o0 = MFMA16(pf[s8],     vf[s8],     o0);
            o1 = MFMA16(pf[s8 + 4], vf[s8 + 4], o1);
        }

        // row-sum reduction (per q = lane&15), overlapped with PV execution
        float s = (s0 + s1) + (s2 + s3);
        s += __shfl_xor(s, 16, 64);
        s += __shfl_xor(s, 32, 64);
        float inv = 1.0f / s;

        // o rows are q = quad*4+r -> fetch matching inv cross-lane (all lanes
        // participate in the shuffles; divergent branch only on the write)
        float invr[4];
        #pragma unroll
        for (int r = 0; r < 4; ++r)
            invr[r] = __shfl(inv, quad*4 + r, 16);

        // write C' strip: lane holds out[q=quad*4+r][e=l&15<8]
        if (q16 < 8){
            #pragma unroll
            for (int r = 0; r < 4; ++r){
                int row = qs*16 + quad*4 + r;
                smem[CB + row*68 + h*8 + q16] = f2h((o0[r] + o1[r]) * invr[r]);
            }
        }
    }

    __syncthreads();

    // ---- fc: wave w handles output rows w*16..w*16+15 ----
    const int w = h;
    half4 af[4];
    #pragma unroll
    for (int ks = 0; ks < 4; ++ks)
        af[ks] = *(const half4*)(smem + CB + (w*16 + q16)*68 + ks*16 + quad*4);

    #pragma unroll
    for (int nt = 0; nt < 4; ++nt){
        f32x4 a = zz;
        #pragma unroll
        for (int ks = 0; ks < 4; ++ks){
            half4 bf = *(const half4*)(smem + WB + (nt*16 + q16)*68 + ks*16 + quad*4);
            a = MFMA16(af[ks], bf, a);
        }
        float bb = bo[nt*16 + q16];
        #pragma unroll
        for (int r = 0; r < 4; ++r){
            int row = w*16 + quad*4 + r;
            Out[base + (long)row*4096 + nt*16 + q16] = a[r] + bb;
        }
    }
}

extern "C" void kernel_launch(void* const* d_in, const int* in_sizes, int n_in,
                              void* d_out, int out_size, void* d_ws, size_t ws_size,
                              hipStream_t stream)
{
    const float* V  = (const float*)d_in[0];
    const float* K  = (const float*)d_in[1];
    const float* Q  = (const float*)d_in[2];
    const float* Wv = (const float*)d_in[3];
    const float* Wk = (const float*)d_in[4];
    const float* Wq = (const float*)d_in[5];
    const float* Wo = (const float*)d_in[6];
    const float* bo = (const float*)d_in[7];

    sattn_kernel<<<dim3(512), dim3(512), 0, stream>>>(
        V, K, Q, Wv, Wk, Wq, Wo, bo, (float*)d_out);
}

// Round 2
// 110.869 us; speedup vs baseline: 1.0300x; 1.0300x over previous
//
#include <hip/hip_runtime.h>

// Problem constants: B=8, N=128, T=64, EMBED=64, HEADS=8, HEAD_DIM=8
// V/K/Q/Out layout: (b, n, t, c) fp32, element strides (524288, 4096, 64, 1).
// MFMA version (114.8us): E^T = K'Q'^T trick keeps P in A-layout for PV.
// Round-7 (114.2us): strip-critical-path restructure -> NULL. Not the bottleneck.
// Round-8 (this): VGPR-spill theory. launch_bounds(512,4) caps at 128 VGPR;
//   old staging hoisted 48 loop-invariant float4 weight rows (~192 floats live)
//   -> certain spill; attention held ~115 live. Diet:
//   - staging = 6 passes (K/V/Q x 2 cells), each pass touches only its own
//     16 uniform weight float4s (s_load, SGPRs); 12 input float4s issued
//     up-front so HBM latency stays hidden. Peak ~90 VGPR.
//   - attention E-MFMAs in two groups of 4 (acc 32->16 regs); group-B MFMA
//     overlaps group-A exp2 (separate pipes). Peak ~100 VGPR.

typedef _Float16 half4 __attribute__((ext_vector_type(4)));
typedef float    f32x4 __attribute__((ext_vector_type(4)));

#define MFMA16(a,b,c) __builtin_amdgcn_mfma_f32_16x16x16f16((a),(b),(c),0,0,0)

__device__ __forceinline__ unsigned short f2h(float f){
    union { _Float16 h; unsigned short u; } c; c.h = (_Float16)f; return c.u;
}

// LDS offsets in halves (ushort units). Total 37640 halves = 75280 B -> 2 blocks/CU.
#define ZS 0          //    8 halves zero scratch (b64-read target for padded lanes)
#define KB 8          // K' per head: [128 k][8 d]            8*1024
#define QB 8200       // Q' per head: [128 q][8 d] (pre-scaled by sc)
#define VB 16392      // V'^T per head: [8 e][128 k]
#define CB 24584      // C': [128 n][68]  (stride 68 -> conflict-free fc reads)
#define WB 33288      // Wo: [64 o][68]
#define LDS_TOTAL 37640

__device__ __forceinline__ void proj8(const float4 a, const float4 b,
                                      const float* __restrict__ W,
                                      float scale, float out[8])
{
    #pragma unroll
    for (int e = 0; e < 8; ++e){
        float4 w0 = *(const float4*)(W + e*8);
        float4 w1 = *(const float4*)(W + e*8 + 4);
        out[e] = (a.x*w0.x + a.y*w0.y + a.z*w0.z + a.w*w0.w
                + b.x*w1.x + b.y*w1.y + b.z*w1.z + b.w*w1.w) * scale;
    }
}

__global__ __launch_bounds__(512, 4)
void sattn_kernel(const float* __restrict__ V,
                  const float* __restrict__ K,
                  const float* __restrict__ Q,
                  const float* __restrict__ Wv,
                  const float* __restrict__ Wk,
                  const float* __restrict__ Wq,
                  const float* __restrict__ Wo,
                  const float* __restrict__ bo,
                  float* __restrict__ Out)
{
    __shared__ __align__(16) unsigned short smem[LDS_TOTAL];

    const int tid  = threadIdx.x;
    const int bid  = blockIdx.x;
    const int b    = bid >> 6;
    const int t    = bid & 63;
    const long base = (long)b * 524288 + t * 64;
    const float SC = 0.18033688011112043f;   // (1/8) * log2(e), folded into Q'

    // ---- zero scratch ----
    if (tid < 4) *(unsigned int*)(smem + tid*2) = 0u;

    // ---- stage Wo f16 [64 o][68] ----
    {
        int o = tid >> 3, c8 = tid & 7;
        const float* ws = Wo + o*64 + c8*8;
        float4 a = *(const float4*)ws;
        float4 d = *(const float4*)(ws + 4);
        half4 h0; h0.x=(_Float16)a.x; h0.y=(_Float16)a.y; h0.z=(_Float16)a.z; h0.w=(_Float16)a.w;
        half4 h1; h1.x=(_Float16)d.x; h1.y=(_Float16)d.y; h1.z=(_Float16)d.z; h1.w=(_Float16)d.w;
        *(half4*)(smem + WB + o*68 + c8*8)     = h0;   // 8-B aligned
        *(half4*)(smem + WB + o*68 + c8*8 + 4) = h1;
    }

    // ---- stage projected K', Q' (x sc), V'^T as f16 ----
    // cell 0: (cn0, ch), cell 1: (cn0+64, ch). All 12 global float4 loads
    // issued up-front (HBM latency hidden); then 6 low-pressure passes.
    {
        const int cn0 = tid >> 3, ch = tid & 7;
        const float* p0 = K + base + cn0*4096 + ch*8;
        const float* p1 = V + base + cn0*4096 + ch*8;
        const float* p2 = Q + base + cn0*4096 + ch*8;
        float4 k0a = *(const float4*)p0,        k0b = *(const float4*)(p0+4);
        float4 v0a = *(const float4*)p1,        v0b = *(const float4*)(p1+4);
        float4 q0a = *(const float4*)p2,        q0b = *(const float4*)(p2+4);
        float4 k1a = *(const float4*)(p0+262144), k1b = *(const float4*)(p0+262148);
        float4 v1a = *(const float4*)(p1+262144), v1b = *(const float4*)(p1+262148);
        float4 q1a = *(const float4*)(p2+262144), q1b = *(const float4*)(p2+262148);

        float o8[8];

        // K cell 0
        proj8(k0a, k0b, Wk, 1.0f, o8);
        {
            half4 h0; h0.x=(_Float16)o8[0]; h0.y=(_Float16)o8[1]; h0.z=(_Float16)o8[2]; h0.w=(_Float16)o8[3];
            half4 h1; h1.x=(_Float16)o8[4]; h1.y=(_Float16)o8[5]; h1.z=(_Float16)o8[6]; h1.w=(_Float16)o8[7];
            *(half4*)(smem + KB + ch*1024 + cn0*8)     = h0;
            *(half4*)(smem + KB + ch*1024 + cn0*8 + 4) = h1;
        }
        // K cell 1
        proj8(k1a, k1b, Wk, 1.0f, o8);
        {
            half4 h0; h0.x=(_Float16)o8[0]; h0.y=(_Float16)o8[1]; h0.z=(_Float16)o8[2]; h0.w=(_Float16)o8[3];
            half4 h1; h1.x=(_Float16)o8[4]; h1.y=(_Float16)o8[5]; h1.z=(_Float16)o8[6]; h1.w=(_Float16)o8[7];
            *(half4*)(smem + KB + ch*1024 + (cn0+64)*8)     = h0;
            *(half4*)(smem + KB + ch*1024 + (cn0+64)*8 + 4) = h1;
        }
        // Q cell 0 (x SC)
        proj8(q0a, q0b, Wq, SC, o8);
        {
            half4 h0; h0.x=(_Float16)o8[0]; h0.y=(_Float16)o8[1]; h0.z=(_Float16)o8[2]; h0.w=(_Float16)o8[3];
            half4 h1; h1.x=(_Float16)o8[4]; h1.y=(_Float16)o8[5]; h1.z=(_Float16)o8[6]; h1.w=(_Float16)o8[7];
            *(half4*)(smem + QB + ch*1024 + cn0*8)     = h0;
            *(half4*)(smem + QB + ch*1024 + cn0*8 + 4) = h1;
        }
        // Q cell 1 (x SC)
        proj8(q1a, q1b, Wq, SC, o8);
        {
            half4 h0; h0.x=(_Float16)o8[0]; h0.y=(_Float16)o8[1]; h0.z=(_Float16)o8[2]; h0.w=(_Float16)o8[3];
            half4 h1; h1.x=(_Float16)o8[4]; h1.y=(_Float16)o8[5]; h1.z=(_Float16)o8[6]; h1.w=(_Float16)o8[7];
            *(half4*)(smem + QB + ch*1024 + (cn0+64)*8)     = h0;
            *(half4*)(smem + QB + ch*1024 + (cn0+64)*8 + 4) = h1;
        }
        // V cell 0 (transposed scatter)
        proj8(v0a, v0b, Wv, 1.0f, o8);
        #pragma unroll
        for (int e = 0; e < 8; ++e)
            smem[VB + ch*1024 + e*128 + cn0] = f2h(o8[e]);
        // V cell 1
        proj8(v1a, v1b, Wv, 1.0f, o8);
        #pragma unroll
        for (int e = 0; e < 8; ++e)
            smem[VB + ch*1024 + e*128 + cn0 + 64] = f2h(o8[e]);
    }

    __syncthreads();

    // ---- attention: wave = head h ----
    const int h    = tid >> 6;
    const int q16  = tid & 15;          // lane & 15
    const int quad = (tid & 63) >> 4;   // lane >> 4
    const f32x4 zz = {0.f, 0.f, 0.f, 0.f};

    // K' A-fragments (8 k-tiles, held): A[m=l&15][k=quad*4+i], quads 2,3 -> zero
    half4 kf[8];
    #pragma unroll
    for (int mt = 0; mt < 8; ++mt){
        int a = KB + h*1024 + (mt*16 + q16)*8 + quad*4;
        if (quad >= 2) a = ZS;
        kf[mt] = *(const half4*)(smem + a);
    }
    // V'^T B-fragments (8 k-steps, held): B[k=quad*4+i][n=e=l&15], e>=8 -> zero
    half4 vf[8];
    #pragma unroll
    for (int s = 0; s < 8; ++s){
        int a = VB + h*1024 + q16*128 + s*16 + quad*4;
        if (q16 >= 8) a = ZS;
        vf[s] = *(const half4*)(smem + a);
    }

    #pragma unroll 1
    for (int qs = 0; qs < 8; ++qs){
        // Q' B-fragment for this strip: B[k=d][n=q], quads 2,3 -> zero
        int qa = QB + h*1024 + (qs*16 + q16)*8 + quad*4;
        if (quad >= 2) qa = ZS;
        half4 qf = *(const half4*)(smem + qa);

        half4 pf[8];
        float s0 = 0.f, s1 = 0.f, s2 = 0.f, s3 = 0.f;

        // E^T group A (mt 0..3): 4 independent MFMAs, then exp2+pack
        {
            f32x4 acc[4];
            #pragma unroll
            for (int mt = 0; mt < 4; ++mt)
                acc[mt] = MFMA16(kf[mt], qf, zz);
            #pragma unroll
            for (int mt = 0; mt < 4; ++mt){
                float p0 = __builtin_amdgcn_exp2f(acc[mt][0]);
                float p1 = __builtin_amdgcn_exp2f(acc[mt][1]);
                float p2 = __builtin_amdgcn_exp2f(acc[mt][2]);
                float p3 = __builtin_amdgcn_exp2f(acc[mt][3]);
                s0 += p0; s1 += p1; s2 += p2; s3 += p3;
                pf[mt].x = (_Float16)p0; pf[mt].y = (_Float16)p1;
                pf[mt].z = (_Float16)p2; pf[mt].w = (_Float16)p3;
            }
        }
        // E^T group B (mt 4..7): overlaps group-A exp2 on the trans pipe
        {
            f32x4 acc[4];
            #pragma unroll
            for (int mt = 0; mt < 4; ++mt)
                acc[mt] = MFMA16(kf[mt+4], qf, zz);
            #pragma unroll
            for (int mt = 0; mt < 4; ++mt){
                float p0 = __builtin_amdgcn_exp2f(acc[mt][0]);
                float p1 = __builtin_amdgcn_exp2f(acc[mt][1]);
                float p2 = __builtin_amdgcn_exp2f(acc[mt][2]);
                float p3 = __builtin_amdgcn_exp2f(acc[mt][3]);
                s0 += p0; s1 += p1; s2 += p2; s3 += p3;
                pf[mt+4].x = (_Float16)p0; pf[mt+4].y = (_Float16)p1;
                pf[mt+4].z = (_Float16)p2; pf[mt+4].w = (_Float16)p3;
            }
        }

        // PV: two 4-deep chains (P unnormalized; scale at the end)
        f32x4 o0 = zz, o1 = zz;
        #pragma unroll
        for (int s8 = 0; s8 < 4; ++s8){
            o0 = MFMA16(pf[s8],     vf[s8],     o0);
            o1 = MFMA16(pf[s8 + 4], vf[s8 + 4], o1);
        }

        // row-sum reduction (per q = lane&15), overlapped with PV execution
        float s = (s0 + s1) + (s2 + s3);
        s += __shfl_xor(s, 16, 64);
        s += __shfl_xor(s, 32, 64);
        float inv = 1.0f / s;

        // o rows are q = quad*4+r -> fetch matching inv cross-lane
        float invr[4];
        #pragma unroll
        for (int r = 0; r < 4; ++r)
            invr[r] = __shfl(inv, quad*4 + r, 16);

        // write C' strip: lane holds out[q=quad*4+r][e=l&15<8]
        if (q16 < 8){
            #pragma unroll
            for (int r = 0; r < 4; ++r){
                int row = qs*16 + quad*4 + r;
                smem[CB + row*68 + h*8 + q16] = f2h((o0[r] + o1[r]) * invr[r]);
            }
        }
    }

    __syncthreads();

    // ---- fc: wave w handles output rows w*16..w*16+15 ----
    const int w = h;
    half4 af[4];
    #pragma unroll
    for (int ks = 0; ks < 4; ++ks)
        af[ks] = *(const half4*)(smem + CB + (w*16 + q16)*68 + ks*16 + quad*4);

    #pragma unroll
    for (int nt = 0; nt < 4; ++nt){
        f32x4 a = zz;
        #pragma unroll
        for (int ks = 0; ks < 4; ++ks){
            half4 bf = *(const half4*)(smem + WB + (nt*16 + q16)*68 + ks*16 + quad*4);
            a = MFMA16(af[ks], bf, a);
        }
        float bb = bo[nt*16 + q16];
        #pragma unroll
        for (int r = 0; r < 4; ++r){
            int row = w*16 + quad*4 + r;
            Out[base + (long)row*4096 + nt*16 + q16] = a[r] + bb;
        }
    }
}

extern "C" void kernel_launch(void* const* d_in, const int* in_sizes, int n_in,
                              void* d_out, int out_size, void* d_ws, size_t ws_size,
                              hipStream_t stream)
{
    const float* V  = (const float*)d_in[0];
    const float* K  = (const float*)d_in[1];
    const float* Q  = (const float*)d_in[2];
    const float* Wv = (const float*)d_in[3];
    const float* Wk = (const float*)d_in[4];
    const float* Wq = (const float*)d_in[5];
    const float* Wo = (const float*)d_in[6];
    const float* bo = (const float*)d_in[7];

    sattn_kernel<<<dim3(512), dim3(512), 0, stream>>>(
        V, K, Q, Wv, Wk, Wq, Wo, bo, (float*)d_out);
}

// Round 3
// 110.330 us; speedup vs baseline: 1.0350x; 1.0049x over previous
//
#include <hip/hip_runtime.h>

// Problem constants: B=8, N=128, T=64, EMBED=64, HEADS=8, HEAD_DIM=8
// V/K/Q/Out layout: (b, n, t, c) fp32, element strides (524288, 4096, 64, 1).
// MFMA version (114.8us): E^T = K'Q'^T trick keeps P in A-layout for PV.
// Round-7 (114.2us): strip-critical-path restructure -> NULL (not latency-bound).
// Round-8 (110.9us): staging/attention register diet -> real -3.3us (VALU/spill).
// Round-9 (this): attention VALU-throughput cut via MFMA-computed softmax
//   denominators: V'^T's padded e=8 column is set to ONES, so PV's output
//   column 8 accumulates sum_k P[k][q] in the matrix pipe. Deletes 32 adds +
//   2 shfl_xor per strip and the exp2->sum serial chain; inv = 4 shfl + 4
//   v_rcp (lane quad*16+8 holds the denom). ~90 -> ~55 VALU/strip.
// Note: grid is 512 blocks on 256 CUs = 2 blocks/CU resident by construction;
//   occupancy-capacity work (3 blocks/CU) cannot help this grid.

typedef _Float16 half4 __attribute__((ext_vector_type(4)));
typedef float    f32x4 __attribute__((ext_vector_type(4)));

#define MFMA16(a,b,c) __builtin_amdgcn_mfma_f32_16x16x16f16((a),(b),(c),0,0,0)

__device__ __forceinline__ unsigned short f2h(float f){
    union { _Float16 h; unsigned short u; } c; c.h = (_Float16)f; return c.u;
}

// LDS offsets in halves (ushort units). Total 37648 halves = 75296 B -> 2 blocks/CU.
#define ZS 0          //    8 halves zero scratch (b64-read target for padded lanes)
#define OS 8          //    8 halves ONES scratch (denominator column for PV)
#define KB 16         // K' per head: [128 k][8 d]            8*1024
#define QB 8208       // Q' per head: [128 q][8 d] (pre-scaled by sc)
#define VB 16400      // V'^T per head: [8 e][128 k]
#define CB 24592      // C': [128 n][68]  (stride 68 -> conflict-free fc reads)
#define WB 33296      // Wo: [64 o][68]
#define LDS_TOTAL 37648

__device__ __forceinline__ void proj8(const float4 a, const float4 b,
                                      const float* __restrict__ W,
                                      float scale, float out[8])
{
    #pragma unroll
    for (int e = 0; e < 8; ++e){
        float4 w0 = *(const float4*)(W + e*8);
        float4 w1 = *(const float4*)(W + e*8 + 4);
        out[e] = (a.x*w0.x + a.y*w0.y + a.z*w0.z + a.w*w0.w
                + b.x*w1.x + b.y*w1.y + b.z*w1.z + b.w*w1.w) * scale;
    }
}

__global__ __launch_bounds__(512, 4)
void sattn_kernel(const float* __restrict__ V,
                  const float* __restrict__ K,
                  const float* __restrict__ Q,
                  const float* __restrict__ Wv,
                  const float* __restrict__ Wk,
                  const float* __restrict__ Wq,
                  const float* __restrict__ Wo,
                  const float* __restrict__ bo,
                  float* __restrict__ Out)
{
    __shared__ __align__(16) unsigned short smem[LDS_TOTAL];

    const int tid  = threadIdx.x;
    const int bid  = blockIdx.x;
    const int b    = bid >> 6;
    const int t    = bid & 63;
    const long base = (long)b * 524288 + t * 64;
    const float SC = 0.18033688011112043f;   // (1/8) * log2(e), folded into Q'

    // ---- zero scratch + ones scratch ----
    if (tid < 4)      *(unsigned int*)(smem + tid*2) = 0u;
    else if (tid < 8) *(unsigned int*)(smem + tid*2) = 0x3C003C00u;  // {1.0h,1.0h}

    // ---- stage Wo f16 [64 o][68] ----
    {
        int o = tid >> 3, c8 = tid & 7;
        const float* ws = Wo + o*64 + c8*8;
        float4 a = *(const float4*)ws;
        float4 d = *(const float4*)(ws + 4);
        half4 h0; h0.x=(_Float16)a.x; h0.y=(_Float16)a.y; h0.z=(_Float16)a.z; h0.w=(_Float16)a.w;
        half4 h1; h1.x=(_Float16)d.x; h1.y=(_Float16)d.y; h1.z=(_Float16)d.z; h1.w=(_Float16)d.w;
        *(half4*)(smem + WB + o*68 + c8*8)     = h0;   // 8-B aligned
        *(half4*)(smem + WB + o*68 + c8*8 + 4) = h1;
    }

    // ---- stage projected K', Q' (x sc), V'^T as f16 ----
    // cell 0: (cn0, ch), cell 1: (cn0+64, ch). All 12 global float4 loads
    // issued up-front (HBM latency hidden); then 6 low-pressure passes.
    {
        const int cn0 = tid >> 3, ch = tid & 7;
        const float* p0 = K + base + cn0*4096 + ch*8;
        const float* p1 = V + base + cn0*4096 + ch*8;
        const float* p2 = Q + base + cn0*4096 + ch*8;
        float4 k0a = *(const float4*)p0,        k0b = *(const float4*)(p0+4);
        float4 v0a = *(const float4*)p1,        v0b = *(const float4*)(p1+4);
        float4 q0a = *(const float4*)p2,        q0b = *(const float4*)(p2+4);
        float4 k1a = *(const float4*)(p0+262144), k1b = *(const float4*)(p0+262148);
        float4 v1a = *(const float4*)(p1+262144), v1b = *(const float4*)(p1+262148);
        float4 q1a = *(const float4*)(p2+262144), q1b = *(const float4*)(p2+262148);

        float o8[8];

        // K cell 0
        proj8(k0a, k0b, Wk, 1.0f, o8);
        {
            half4 h0; h0.x=(_Float16)o8[0]; h0.y=(_Float16)o8[1]; h0.z=(_Float16)o8[2]; h0.w=(_Float16)o8[3];
            half4 h1; h1.x=(_Float16)o8[4]; h1.y=(_Float16)o8[5]; h1.z=(_Float16)o8[6]; h1.w=(_Float16)o8[7];
            *(half4*)(smem + KB + ch*1024 + cn0*8)     = h0;
            *(half4*)(smem + KB + ch*1024 + cn0*8 + 4) = h1;
        }
        // K cell 1
        proj8(k1a, k1b, Wk, 1.0f, o8);
        {
            half4 h0; h0.x=(_Float16)o8[0]; h0.y=(_Float16)o8[1]; h0.z=(_Float16)o8[2]; h0.w=(_Float16)o8[3];
            half4 h1; h1.x=(_Float16)o8[4]; h1.y=(_Float16)o8[5]; h1.z=(_Float16)o8[6]; h1.w=(_Float16)o8[7];
            *(half4*)(smem + KB + ch*1024 + (cn0+64)*8)     = h0;
            *(half4*)(smem + KB + ch*1024 + (cn0+64)*8 + 4) = h1;
        }
        // Q cell 0 (x SC)
        proj8(q0a, q0b, Wq, SC, o8);
        {
            half4 h0; h0.x=(_Float16)o8[0]; h0.y=(_Float16)o8[1]; h0.z=(_Float16)o8[2]; h0.w=(_Float16)o8[3];
            half4 h1; h1.x=(_Float16)o8[4]; h1.y=(_Float16)o8[5]; h1.z=(_Float16)o8[6]; h1.w=(_Float16)o8[7];
            *(half4*)(smem + QB + ch*1024 + cn0*8)     = h0;
            *(half4*)(smem + QB + ch*1024 + cn0*8 + 4) = h1;
        }
        // Q cell 1 (x SC)
        proj8(q1a, q1b, Wq, SC, o8);
        {
            half4 h0; h0.x=(_Float16)o8[0]; h0.y=(_Float16)o8[1]; h0.z=(_Float16)o8[2]; h0.w=(_Float16)o8[3];
            half4 h1; h1.x=(_Float16)o8[4]; h1.y=(_Float16)o8[5]; h1.z=(_Float16)o8[6]; h1.w=(_Float16)o8[7];
            *(half4*)(smem + QB + ch*1024 + (cn0+64)*8)     = h0;
            *(half4*)(smem + QB + ch*1024 + (cn0+64)*8 + 4) = h1;
        }
        // V cell 0 (transposed scatter)
        proj8(v0a, v0b, Wv, 1.0f, o8);
        #pragma unroll
        for (int e = 0; e < 8; ++e)
            smem[VB + ch*1024 + e*128 + cn0] = f2h(o8[e]);
        // V cell 1
        proj8(v1a, v1b, Wv, 1.0f, o8);
        #pragma unroll
        for (int e = 0; e < 8; ++e)
            smem[VB + ch*1024 + e*128 + cn0 + 64] = f2h(o8[e]);
    }

    __syncthreads();

    // ---- attention: wave = head h ----
    const int h    = tid >> 6;
    const int q16  = tid & 15;          // lane & 15
    const int quad = (tid & 63) >> 4;   // lane >> 4
    const f32x4 zz = {0.f, 0.f, 0.f, 0.f};

    // K' A-fragments (8 k-tiles, held): A[m=l&15][k=quad*4+i], quads 2,3 -> zero
    half4 kf[8];
    #pragma unroll
    for (int mt = 0; mt < 8; ++mt){
        int a = KB + h*1024 + (mt*16 + q16)*8 + quad*4;
        if (quad >= 2) a = ZS;
        kf[mt] = *(const half4*)(smem + a);
    }
    // V'^T B-fragments (8 k-steps, held): B[k=quad*4+i][n=e=l&15]
    // e==8 -> ONES (denominator column), e>8 -> zero
    half4 vf[8];
    #pragma unroll
    for (int s = 0; s < 8; ++s){
        int a = VB + h*1024 + q16*128 + s*16 + quad*4;
        if (q16 > 8)  a = ZS;
        if (q16 == 8) a = OS;
        vf[s] = *(const half4*)(smem + a);
    }

    #pragma unroll 1
    for (int qs = 0; qs < 8; ++qs){
        // Q' B-fragment for this strip: B[k=d][n=q], quads 2,3 -> zero
        int qa = QB + h*1024 + (qs*16 + q16)*8 + quad*4;
        if (quad >= 2) qa = ZS;
        half4 qf = *(const half4*)(smem + qa);

        half4 pf[8];

        // E^T group A (mt 0..3): 4 independent MFMAs, exp2+pack (no sum chain)
        {
            f32x4 acc[4];
            #pragma unroll
            for (int mt = 0; mt < 4; ++mt)
                acc[mt] = MFMA16(kf[mt], qf, zz);
            #pragma unroll
            for (int mt = 0; mt < 4; ++mt){
                pf[mt].x = (_Float16)__builtin_amdgcn_exp2f(acc[mt][0]);
                pf[mt].y = (_Float16)__builtin_amdgcn_exp2f(acc[mt][1]);
                pf[mt].z = (_Float16)__builtin_amdgcn_exp2f(acc[mt][2]);
                pf[mt].w = (_Float16)__builtin_amdgcn_exp2f(acc[mt][3]);
            }
        }
        // E^T group B (mt 4..7)
        {
            f32x4 acc[4];
            #pragma unroll
            for (int mt = 0; mt < 4; ++mt)
                acc[mt] = MFMA16(kf[mt+4], qf, zz);
            #pragma unroll
            for (int mt = 0; mt < 4; ++mt){
                pf[mt+4].x = (_Float16)__builtin_amdgcn_exp2f(acc[mt][0]);
                pf[mt+4].y = (_Float16)__builtin_amdgcn_exp2f(acc[mt][1]);
                pf[mt+4].z = (_Float16)__builtin_amdgcn_exp2f(acc[mt][2]);
                pf[mt+4].w = (_Float16)__builtin_amdgcn_exp2f(acc[mt][3]);
            }
        }

        // PV: two 4-deep chains. Column e=8 (ones) accumulates the softmax
        // denominator sum_k P[k][q] in the matrix pipe.
        f32x4 o0 = zz, o1 = zz;
        #pragma unroll
        for (int s8 = 0; s8 < 4; ++s8){
            o0 = MFMA16(pf[s8],     vf[s8],     o0);
            o1 = MFMA16(pf[s8 + 4], vf[s8 + 4], o1);
        }

        // t[r] = O (lanes e<8) or denominator (lane e==8).
        float tr[4];
        #pragma unroll
        for (int r = 0; r < 4; ++r)
            tr[r] = o0[r] + o1[r];

        // inv per output row q=quad*4+r lives at lane (quad*16 + 8)
        const int dl = (tid & 48) + 8;
        float invr[4];
        #pragma unroll
        for (int r = 0; r < 4; ++r)
            invr[r] = __builtin_amdgcn_rcpf(__shfl(tr[r], dl, 64));

        // write C' strip: lane holds out[q=quad*4+r][e=l&15<8]
        if (q16 < 8){
            #pragma unroll
            for (int r = 0; r < 4; ++r){
                int row = qs*16 + quad*4 + r;
                smem[CB + row*68 + h*8 + q16] = f2h(tr[r] * invr[r]);
            }
        }
    }

    __syncthreads();

    // ---- fc: wave w handles output rows w*16..w*16+15 ----
    const int w = h;
    half4 af[4];
    #pragma unroll
    for (int ks = 0; ks < 4; ++ks)
        af[ks] = *(const half4*)(smem + CB + (w*16 + q16)*68 + ks*16 + quad*4);

    #pragma unroll
    for (int nt = 0; nt < 4; ++nt){
        f32x4 a = zz;
        #pragma unroll
        for (int ks = 0; ks < 4; ++ks){
            half4 bf = *(const half4*)(smem + WB + (nt*16 + q16)*68 + ks*16 + quad*4);
            a = MFMA16(af[ks], bf, a);
        }
        float bb = bo[nt*16 + q16];
        #pragma unroll
        for (int r = 0; r < 4; ++r){
            int row = w*16 + quad*4 + r;
            Out[base + (long)row*4096 + nt*16 + q16] = a[r] + bb;
        }
    }
}

extern "C" void kernel_launch(void* const* d_in, const int* in_sizes, int n_in,
                              void* d_out, int out_size, void* d_ws, size_t ws_size,
                              hipStream_t stream)
{
    const float* V  = (const float*)d_in[0];
    const float* K  = (const float*)d_in[1];
    const float* Q  = (const float*)d_in[2];
    const float* Wv = (const float*)d_in[3];
    const float* Wk = (const float*)d_in[4];
    const float* Wq = (const float*)d_in[5];
    const float* Wo = (const float*)d_in[6];
    const float* bo = (const float*)d_in[7];

    sattn_kernel<<<dim3(512), dim3(512), 0, stream>>>(
        V, K, Q, Wv, Wk, Wq, Wo, bo, (float*)d_out);
}

// Round 4
// 109.508 us; speedup vs baseline: 1.0428x; 1.0075x over previous
//
#include <hip/hip_runtime.h>

// Problem constants: B=8, N=128, T=64, EMBED=64, HEADS=8, HEAD_DIM=8
// V/K/Q/Out layout: (b, n, t, c) fp32, element strides (524288, 4096, 64, 1).
// History: 114.8 MFMA base -> R0 latency restructure NULL -> R1 reg diet -3.3
//   -> R2 MFMA-denominator softmax -0.5 (attention VALU not the bottleneck).
// R3 (this): LDS bank conflicts + weight folding.
//   - V^T old layout [e][128] had 16-way conflicts on BOTH the b16 scatter
//     writes (bank = cn/2 only) and the vf b64 reads (64*q16 mod 32 = 0).
//     New layout [d][136], head stride 1096: write bank = 4ch+4d+cn/2 ->
//     2-way (free); read ~2-way.
//   - Weight folding: E = K*(SC*Wk^T*Wq)*Qraw^T  (only K projected, by M;
//     Q staged raw), out = attn(Vraw) * (Wo*blockdiag(Wv))^T  (V staged raw,
//     Wv folded into W2). Deletes Q/V projections (~290 FMA/thread), adds
//     W2 build (64 FMA) + tiny M build (tid<64).

typedef _Float16 half4 __attribute__((ext_vector_type(4)));
typedef float    f32x4 __attribute__((ext_vector_type(4)));

#define MFMA16(a,b,c) __builtin_amdgcn_mfma_f32_16x16x16f16((a),(b),(c),0,0,0)

__device__ __forceinline__ unsigned short f2h(float f){
    union { _Float16 h; unsigned short u; } c; c.h = (_Float16)f; return c.u;
}
__device__ __forceinline__ float dot4(const float4 a, const float4 b){
    return a.x*b.x + a.y*b.y + a.z*b.z + a.w*b.w;
}

// LDS offsets in halves (ushort units). Total 38352 halves = 76704 B -> 2 blocks/CU.
#define ZS 0          //    8 halves zero scratch (b64-read target for padded lanes)
#define OS 8          //    8 halves ONES scratch (denominator column for PV)
#define MB 16         //  128 halves: MT f32 [8 d'][8 d] (M^T, SC folded)
#define KB 144        // KM per head: [128 k][8 d'], head stride 1024
#define QB 8336       // Q raw per head: [128 q][8 d'], head stride 1024
#define VB 16528      // V raw ^T per head: [8 d][136], head stride 1096
#define CB 25296      // C: [128 n][68]  (stride 68 -> conflict-free fc reads)
#define WB 34000      // W2 = Wo*blockdiag(Wv): [64 o][68]
#define LDS_TOTAL 38352

__global__ __launch_bounds__(512, 4)
void sattn_kernel(const float* __restrict__ V,
                  const float* __restrict__ K,
                  const float* __restrict__ Q,
                  const float* __restrict__ Wv,
                  const float* __restrict__ Wk,
                  const float* __restrict__ Wq,
                  const float* __restrict__ Wo,
                  const float* __restrict__ bo,
                  float* __restrict__ Out)
{
    __shared__ __align__(16) unsigned short smem[LDS_TOTAL];

    const int tid  = threadIdx.x;
    const int bid  = blockIdx.x;
    const int b    = bid >> 6;
    const int t    = bid & 63;
    const long base = (long)b * 524288 + t * 64;
    const float SC = 0.18033688011112043f;   // (1/8) * log2(e), folded into M

    const int cn0 = tid >> 3, ch = tid & 7;

    // ---- issue all 12 input float4 loads up-front (HBM latency hidden) ----
    const float* p0 = K + base + cn0*4096 + ch*8;
    const float* p1 = V + base + cn0*4096 + ch*8;
    const float* p2 = Q + base + cn0*4096 + ch*8;
    float4 k0a = *(const float4*)p0,          k0b = *(const float4*)(p0+4);
    float4 v0a = *(const float4*)p1,          v0b = *(const float4*)(p1+4);
    float4 q0a = *(const float4*)p2,          q0b = *(const float4*)(p2+4);
    float4 k1a = *(const float4*)(p0+262144), k1b = *(const float4*)(p0+262148);
    float4 v1a = *(const float4*)(p1+262144), v1b = *(const float4*)(p1+262148);
    float4 q1a = *(const float4*)(p2+262144), q1b = *(const float4*)(p2+262148);

    // ---- zero scratch + ones scratch ----
    if (tid < 4)      *(unsigned int*)(smem + tid*2) = 0u;
    else if (tid < 8) *(unsigned int*)(smem + tid*2) = 0x3C003C00u;  // {1.0h,1.0h}

    // ---- build W2 = Wo * blockdiag(Wv x8), f16 [64 o][68] ----
    // thread (o = tid>>3, g = tid&7) computes W2[o][g*8 + d], d=0..7
    {
        const int o = tid >> 3, g = tid & 7;
        const float* ws = Wo + o*64 + g*8;
        float4 woa = *(const float4*)ws;
        float4 wob = *(const float4*)(ws + 4);
        float wo8[8] = {woa.x, woa.y, woa.z, woa.w, wob.x, wob.y, wob.z, wob.w};
        float w2[8] = {0,0,0,0,0,0,0,0};
        #pragma unroll
        for (int e = 0; e < 8; ++e){
            float4 wv0 = *(const float4*)(Wv + e*8);
            float4 wv1 = *(const float4*)(Wv + e*8 + 4);
            float we = wo8[e];
            w2[0] += we*wv0.x; w2[1] += we*wv0.y; w2[2] += we*wv0.z; w2[3] += we*wv0.w;
            w2[4] += we*wv1.x; w2[5] += we*wv1.y; w2[6] += we*wv1.z; w2[7] += we*wv1.w;
        }
        half4 h0; h0.x=(_Float16)w2[0]; h0.y=(_Float16)w2[1]; h0.z=(_Float16)w2[2]; h0.w=(_Float16)w2[3];
        half4 h1; h1.x=(_Float16)w2[4]; h1.y=(_Float16)w2[5]; h1.z=(_Float16)w2[6]; h1.w=(_Float16)w2[7];
        *(half4*)(smem + WB + o*68 + g*8)     = h0;
        *(half4*)(smem + WB + o*68 + g*8 + 4) = h1;
    }

    // ---- build MT[d'][d] = SC * sum_e Wk[e][d]*Wq[e][d'], f32 in LDS ----
    if (tid < 64){
        const int dd = tid & 7;    // d  (Wk column)
        const int dp = tid >> 3;   // d' (Wq column)
        float m = 0.f;
        #pragma unroll
        for (int e = 0; e < 8; ++e)
            m += Wk[e*8 + dd] * Wq[e*8 + dp];
        reinterpret_cast<float*>(smem + MB)[tid] = m * SC;   // MT[dp][dd], idx=tid
    }

    // ---- stage RAW Q (f2h only): [128 q][8 d'], head stride 1024 ----
    {
        half4 h0; h0.x=(_Float16)q0a.x; h0.y=(_Float16)q0a.y; h0.z=(_Float16)q0a.z; h0.w=(_Float16)q0a.w;
        half4 h1; h1.x=(_Float16)q0b.x; h1.y=(_Float16)q0b.y; h1.z=(_Float16)q0b.z; h1.w=(_Float16)q0b.w;
        *(half4*)(smem + QB + ch*1024 + cn0*8)     = h0;
        *(half4*)(smem + QB + ch*1024 + cn0*8 + 4) = h1;
        half4 h2; h2.x=(_Float16)q1a.x; h2.y=(_Float16)q1a.y; h2.z=(_Float16)q1a.z; h2.w=(_Float16)q1a.w;
        half4 h3; h3.x=(_Float16)q1b.x; h3.y=(_Float16)q1b.y; h3.z=(_Float16)q1b.z; h3.w=(_Float16)q1b.w;
        *(half4*)(smem + QB + ch*1024 + (cn0+64)*8)     = h2;
        *(half4*)(smem + QB + ch*1024 + (cn0+64)*8 + 4) = h3;
    }

    // ---- stage RAW V transposed: [8 d][136], head stride 1096 ----
    // write bank = (4ch + 4d + cn/2) mod 32 -> 2 lanes/bank (free)
    {
        unsigned short* vb = smem + VB + ch*1096;
        vb[0*136 + cn0] = f2h(v0a.x); vb[1*136 + cn0] = f2h(v0a.y);
        vb[2*136 + cn0] = f2h(v0a.z); vb[3*136 + cn0] = f2h(v0a.w);
        vb[4*136 + cn0] = f2h(v0b.x); vb[5*136 + cn0] = f2h(v0b.y);
        vb[6*136 + cn0] = f2h(v0b.z); vb[7*136 + cn0] = f2h(v0b.w);
        vb[0*136 + cn0+64] = f2h(v1a.x); vb[1*136 + cn0+64] = f2h(v1a.y);
        vb[2*136 + cn0+64] = f2h(v1a.z); vb[3*136 + cn0+64] = f2h(v1a.w);
        vb[4*136 + cn0+64] = f2h(v1b.x); vb[5*136 + cn0+64] = f2h(v1b.y);
        vb[6*136 + cn0+64] = f2h(v1b.z); vb[7*136 + cn0+64] = f2h(v1b.w);
    }

    __syncthreads();   // MT ready

    // ---- project K by MT: KM[k][d'] = sum_d K[k][d]*MT[d'][d] ----
    {
        const float* mt = reinterpret_cast<const float*>(smem + MB);
        float4 m0[8], m1[8];
        #pragma unroll
        for (int dp = 0; dp < 8; ++dp){
            m0[dp] = *(const float4*)(mt + dp*8);
            m1[dp] = *(const float4*)(mt + dp*8 + 4);
        }
        float ok[8];
        #pragma unroll
        for (int dp = 0; dp < 8; ++dp)
            ok[dp] = dot4(k0a, m0[dp]) + dot4(k0b, m1[dp]);
        half4 h0; h0.x=(_Float16)ok[0]; h0.y=(_Float16)ok[1]; h0.z=(_Float16)ok[2]; h0.w=(_Float16)ok[3];
        half4 h1; h1.x=(_Float16)ok[4]; h1.y=(_Float16)ok[5]; h1.z=(_Float16)ok[6]; h1.w=(_Float16)ok[7];
        *(half4*)(smem + KB + ch*1024 + cn0*8)     = h0;
        *(half4*)(smem + KB + ch*1024 + cn0*8 + 4) = h1;
        #pragma unroll
        for (int dp = 0; dp < 8; ++dp)
            ok[dp] = dot4(k1a, m0[dp]) + dot4(k1b, m1[dp]);
        half4 h2; h2.x=(_Float16)ok[0]; h2.y=(_Float16)ok[1]; h2.z=(_Float16)ok[2]; h2.w=(_Float16)ok[3];
        half4 h3; h3.x=(_Float16)ok[4]; h3.y=(_Float16)ok[5]; h3.z=(_Float16)ok[6]; h3.w=(_Float16)ok[7];
        *(half4*)(smem + KB + ch*1024 + (cn0+64)*8)     = h2;
        *(half4*)(smem + KB + ch*1024 + (cn0+64)*8 + 4) = h3;
    }

    __syncthreads();

    // ---- attention: wave = head h ----
    const int h    = tid >> 6;
    const int q16  = tid & 15;          // lane & 15
    const int quad = (tid & 63) >> 4;   // lane >> 4
    const f32x4 zz = {0.f, 0.f, 0.f, 0.f};

    // KM A-fragments (8 k-tiles, held): A[m=l&15][k=quad*4+i], quads 2,3 -> zero
    half4 kf[8];
    #pragma unroll
    for (int mt = 0; mt < 8; ++mt){
        int a = KB + h*1024 + (mt*16 + q16)*8 + quad*4;
        if (quad >= 2) a = ZS;
        kf[mt] = *(const half4*)(smem + a);
    }
    // Vraw^T B-fragments (8 k-steps, held): B[k=quad*4+i][n=d=l&15]
    // d==8 -> ONES (denominator column), d>8 -> zero
    half4 vf[8];
    #pragma unroll
    for (int s = 0; s < 8; ++s){
        int a = VB + h*1096 + q16*136 + s*16 + quad*4;
        if (q16 > 8)  a = ZS;
        if (q16 == 8) a = OS;
        vf[s] = *(const half4*)(smem + a);
    }

    #pragma unroll 1
    for (int qs = 0; qs < 8; ++qs){
        // Qraw B-fragment for this strip: B[k=d'][n=q], quads 2,3 -> zero
        int qa = QB + h*1024 + (qs*16 + q16)*8 + quad*4;
        if (quad >= 2) qa = ZS;
        half4 qf = *(const half4*)(smem + qa);

        half4 pf[8];

        // E^T group A (mt 0..3): 4 independent MFMAs, exp2+pack
        {
            f32x4 acc[4];
            #pragma unroll
            for (int mt = 0; mt < 4; ++mt)
                acc[mt] = MFMA16(kf[mt], qf, zz);
            #pragma unroll
            for (int mt = 0; mt < 4; ++mt){
                pf[mt].x = (_Float16)__builtin_amdgcn_exp2f(acc[mt][0]);
                pf[mt].y = (_Float16)__builtin_amdgcn_exp2f(acc[mt][1]);
                pf[mt].z = (_Float16)__builtin_amdgcn_exp2f(acc[mt][2]);
                pf[mt].w = (_Float16)__builtin_amdgcn_exp2f(acc[mt][3]);
            }
        }
        // E^T group B (mt 4..7)
        {
            f32x4 acc[4];
            #pragma unroll
            for (int mt = 0; mt < 4; ++mt)
                acc[mt] = MFMA16(kf[mt+4], qf, zz);
            #pragma unroll
            for (int mt = 0; mt < 4; ++mt){
                pf[mt+4].x = (_Float16)__builtin_amdgcn_exp2f(acc[mt][0]);
                pf[mt+4].y = (_Float16)__builtin_amdgcn_exp2f(acc[mt][1]);
                pf[mt+4].z = (_Float16)__builtin_amdgcn_exp2f(acc[mt][2]);
                pf[mt+4].w = (_Float16)__builtin_amdgcn_exp2f(acc[mt][3]);
            }
        }

        // PV: two 4-deep chains. Column d=8 (ones) accumulates the softmax
        // denominator sum_k P[k][q] in the matrix pipe.
        f32x4 o0 = zz, o1 = zz;
        #pragma unroll
        for (int s8 = 0; s8 < 4; ++s8){
            o0 = MFMA16(pf[s8],     vf[s8],     o0);
            o1 = MFMA16(pf[s8 + 4], vf[s8 + 4], o1);
        }

        float tr[4];
        #pragma unroll
        for (int r = 0; r < 4; ++r)
            tr[r] = o0[r] + o1[r];

        // inv per output row q=quad*4+r lives at lane (quad*16 + 8)
        const int dl = (tid & 48) + 8;
        float invr[4];
        #pragma unroll
        for (int r = 0; r < 4; ++r)
            invr[r] = __builtin_amdgcn_rcpf(__shfl(tr[r], dl, 64));

        // write C strip: lane holds out[q=quad*4+r][d=l&15<8]
        if (q16 < 8){
            #pragma unroll
            for (int r = 0; r < 4; ++r){
                int row = qs*16 + quad*4 + r;
                smem[CB + row*68 + h*8 + q16] = f2h(tr[r] * invr[r]);
            }
        }
    }

    __syncthreads();

    // ---- fc with W2: wave w handles output rows w*16..w*16+15 ----
    const int w = h;
    half4 af[4];
    #pragma unroll
    for (int ks = 0; ks < 4; ++ks)
        af[ks] = *(const half4*)(smem + CB + (w*16 + q16)*68 + ks*16 + quad*4);

    #pragma unroll
    for (int nt = 0; nt < 4; ++nt){
        f32x4 a = zz;
        #pragma unroll
        for (int ks = 0; ks < 4; ++ks){
            half4 bf = *(const half4*)(smem + WB + (nt*16 + q16)*68 + ks*16 + quad*4);
            a = MFMA16(af[ks], bf, a);
        }
        float bb = bo[nt*16 + q16];
        #pragma unroll
        for (int r = 0; r < 4; ++r){
            int row = w*16 + quad*4 + r;
            Out[base + (long)row*4096 + nt*16 + q16] = a[r] + bb;
        }
    }
}

extern "C" void kernel_launch(void* const* d_in, const int* in_sizes, int n_in,
                              void* d_out, int out_size, void* d_ws, size_t ws_size,
                              hipStream_t stream)
{
    const float* V  = (const float*)d_in[0];
    const float* K  = (const float*)d_in[1];
    const float* Q  = (const float*)d_in[2];
    const float* Wv = (const float*)d_in[3];
    const float* Wk = (const float*)d_in[4];
    const float* Wq = (const float*)d_in[5];
    const float* Wo = (const float*)d_in[6];
    const float* bo = (const float*)d_in[7];

    sattn_kernel<<<dim3(512), dim3(512), 0, stream>>>(
        V, K, Q, Wv, Wk, Wq, Wo, bo, (float*)d_out);
}